// Round 4
// baseline (318.579 us; speedup 1.0000x reference)
//
#include <hip/hip_runtime.h>
#include <hip/hip_bf16.h>
#include <math.h>

// ---------------------------------------------------------------------------
// LeNet forward, B=8192.  bf16 MFMA for conv1/conv2/conv3/fc1; fp32 fc2.
//  x[8192,1,28,28] -conv1(Toeplitz-MFMA)+pool-> p1 bf16 [img][196pix][16ci]
//  p1 -conv2+pool->  p2 bf16 [img][49pix][32ci]
//  p2 -conv3+pool->  p3 bf16 [img][1024] (k = co*16 + pix, ref flatten order)
//  p3 -fc1->         h4 f32  [8192][256]
//  h4 -fc2+lsm->     out f32 [8192][10]
// ---------------------------------------------------------------------------

typedef short bf16x8 __attribute__((ext_vector_type(8)));
typedef float f32x4 __attribute__((ext_vector_type(4)));
typedef unsigned short u16;
#define MFMA16 __builtin_amdgcn_mfma_f32_16x16x32_bf16

__device__ __forceinline__ u16 f2b(float f) {
  __hip_bfloat16 h = __float2bfloat16(f);
  return *reinterpret_cast<u16*>(&h);
}

// ---------------- one pack kernel for all four weight layouts --------------
// Bp2: [c13][nt2][lane64][j8]; k=tap*16+ci; tap=2c+(l>>5), ci=((l>>4)&1)*8+j
// Bp3: [c25][nt4][lane64][j8]; k=tap*32+ci; tap=c, ci=(l>>4)*8+j
// Bp1: [c32][nt16][lane64][j8]; k=c*32+(l>>4)*8+j
// Bp0 (conv1 Toeplitz): [c5=ky][px28][lane64][j8]; x'=(l>>4)*8+j, co=l&15;
//      val = w1[co][ky][x'-px] if 0<=x'-px<5 else 0
__global__ __launch_bounds__(256) void mega_pack(
    const float* __restrict__ w2, const float* __restrict__ w3,
    const float* __restrict__ fw1, const float* __restrict__ w1,
    u16* __restrict__ Bp2, u16* __restrict__ Bp3,
    u16* __restrict__ Bp1, u16* __restrict__ Bp0) {
  int gid = blockIdx.x * 256 + threadIdx.x;   // 398336 total (exact)
  if (gid < 13312) {
    int i = gid;
    int j = i & 7, lane = (i >> 3) & 63, nt = (i >> 9) & 1, c = i >> 10;
    int tap = 2 * c + (lane >> 5);
    int ci = ((lane >> 4) & 1) * 8 + j;
    int co = nt * 16 + (lane & 15);
    float v = (tap < 25) ? w2[co * 400 + ci * 25 + tap] : 0.f;
    Bp2[i] = f2b(v);
  } else if (gid < 64512) {
    int i = gid - 13312;
    int j = i & 7, lane = (i >> 3) & 63, nt = (i >> 9) & 3, c = i >> 11;
    int ci = (lane >> 4) * 8 + j;
    int co = nt * 16 + (lane & 15);
    Bp3[i] = f2b(w3[co * 800 + ci * 25 + c]);
  } else if (gid < 326656) {
    int i = gid - 64512;
    int j = i & 7, lane = (i >> 3) & 63, nt = (i >> 9) & 15, c = i >> 13;
    int k = c * 32 + (lane >> 4) * 8 + j;
    int col = nt * 16 + (lane & 15);
    Bp1[i] = f2b(fw1[col * 1024 + k]);
  } else {
    int i = gid - 326656;                     // 71680
    int j = i & 7, lane = (i >> 3) & 63, pc = i >> 9;
    int px = pc % 28, c = pc / 28;            // c = ky
    int co = lane & 15;
    int xp = (lane >> 4) * 8 + j;
    int kx = xp - px;
    float v = (kx >= 0 && kx < 5) ? w1[co * 25 + c * 5 + kx] : 0.f;
    Bp0[i] = f2b(v);
  }
}

// ---------------- conv1 via Toeplitz MFMA + in-register pool ---------------
// Block = 8 images x 4 px-columns.  M = 8*28 = 224 rows (img-major, py minor),
// N = 4 px * 16 co (N-tile = one px), K = 5 chunks of 32 (ky, x').
// A[m][c*32+x'] = in_pad[img][py+c][x']  -> contiguous b128 row reads.
// Pool pairs: C rows (2q,2q+1) within lane's 4 regs; px pairs = N-tiles (0,1),(2,3).
__global__ __launch_bounds__(256) void conv1_mfma(
    const float* __restrict__ x, const u16* __restrict__ Bp0,
    const float* __restrict__ b1, u16* __restrict__ p1) {
  __shared__ u16 smem[20480];   // img_s [8][32 rows][40 cols] = 10240 ; B_s 10240
  const int bb = blockIdx.x;            // 7168 = 1024 imgG x 7 pxG
  const int imgG = bb / 7, pxG = bb % 7;
  const int pxbase = pxG * 4;
  const int t = threadIdx.x;
  const int w = t >> 6, l = t & 63;
  u16* img_s = smem;
  u16* B_s = smem + 10240;

  const int4 z4 = make_int4(0, 0, 0, 0);
  for (int i = t; i < 1280; i += 256) ((int4*)img_s)[i] = z4;
  for (int i = t; i < 1280; i += 256) {
    int c = i >> 8, rem = i & 255;
    ((int4*)B_s)[c * 256 + rem] =
        ((const int4*)(Bp0 + (size_t)(c * 28 + pxbase) * 512))[rem];
  }
  __syncthreads();
  // fill interior rows 2..29, cols 2..29 (bf16 pairs)
  const float2* xg = (const float2*)(x + (size_t)imgG * 8 * 784);
  for (int i = t; i < 3136; i += 256) {
    int p = i / 14, xc = (i % 14) * 2;
    float2 v = xg[i];
    int img = p / 28, y = p % 28;
    unsigned pk = (unsigned)f2b(v.x) | ((unsigned)f2b(v.y) << 16);
    *(unsigned*)(img_s + img * 1280 + (y + 2) * 40 + xc + 2) = pk;
  }
  __syncthreads();

  const int co = l & 15, g = l >> 4;
  const int nmt = (w < 2) ? 4 : 3;      // M-tiles: w, w+4, w+8, (w+12 if <14)
  int abase[4];
#pragma unroll
  for (int j2 = 0; j2 < 4; ++j2) {
    int mt = w + j2 * 4; if (mt > 13) mt = 13;
    int m = mt * 16 + co;               // A-row = l&15
    int img = m / 28, py = m % 28;
    abase[j2] = img * 1280 + py * 40 + g * 8;
  }
  const float bias = b1[co];
  f32x4 acc[4][4];
#pragma unroll
  for (int j2 = 0; j2 < 4; ++j2)
#pragma unroll
    for (int nt = 0; nt < 4; ++nt)
      acc[j2][nt] = (f32x4){bias, bias, bias, bias};

  for (int c = 0; c < 5; ++c) {
    bf16x8 bf0 = *(const bf16x8*)(B_s + c * 2048 + 0 * 512 + l * 8);
    bf16x8 bf1 = *(const bf16x8*)(B_s + c * 2048 + 1 * 512 + l * 8);
    bf16x8 bf2 = *(const bf16x8*)(B_s + c * 2048 + 2 * 512 + l * 8);
    bf16x8 bf3 = *(const bf16x8*)(B_s + c * 2048 + 3 * 512 + l * 8);
#pragma unroll
    for (int j2 = 0; j2 < 4; ++j2) {
      if (j2 < nmt) {
        bf16x8 a = *(const bf16x8*)(img_s + abase[j2] + c * 40);
        acc[j2][0] = MFMA16(a, bf0, acc[j2][0], 0, 0, 0);
        acc[j2][1] = MFMA16(a, bf1, acc[j2][1], 0, 0, 0);
        acc[j2][2] = MFMA16(a, bf2, acc[j2][2], 0, 0, 0);
        acc[j2][3] = MFMA16(a, bf3, acc[j2][3], 0, 0, 0);
      }
    }
  }
  // epilogue: relu(pool) in regs; write p1 [img][py'*14+px'][16co]
#pragma unroll
  for (int j2 = 0; j2 < 4; ++j2) {
    if (j2 < nmt) {
      int mt = w + j2 * 4;
      int m0 = mt * 16 + g * 4;         // C rows m0..m0+3 (never cross image)
      int img = m0 / 28, py0 = m0 % 28; // py0 even
      size_t base = ((size_t)((imgG * 8 + img) * 196)) << 4;
      int pxp = pxbase >> 1;
#pragma unroll
      for (int half = 0; half < 2; ++half) {
        int r0 = half * 2;
        float vA = fmaxf(fmaxf(acc[j2][0][r0], acc[j2][0][r0 + 1]),
                         fmaxf(acc[j2][1][r0], acc[j2][1][r0 + 1]));
        float vB = fmaxf(fmaxf(acc[j2][2][r0], acc[j2][2][r0 + 1]),
                         fmaxf(acc[j2][3][r0], acc[j2][3][r0 + 1]));
        int pyp = py0 / 2 + half;
        p1[base + (((size_t)pyp * 14 + pxp) << 4) + co]     = f2b(fmaxf(vA, 0.f));
        p1[base + (((size_t)pyp * 14 + pxp + 1) << 4) + co] = f2b(fmaxf(vB, 0.f));
      }
    }
  }
}

// ---------------- conv2 MFMA: 2 img/block, M=392, N=32, K=400(13 chunks) ---
__global__ __launch_bounds__(256) void conv2_mfma(
    const u16* __restrict__ p1, const u16* __restrict__ Bp2,
    const float* __restrict__ b2, u16* __restrict__ p2) {
  __shared__ u16 smem[15552];   // in: 2 x [18][18][24ci-pad] ; out aliases
  const int bb = blockIdx.x;
  const int t = threadIdx.x;
  const int w = t >> 6, l = t & 63;

  for (int i = t; i < 15552; i += 256) smem[i] = 0;
  __syncthreads();
  for (int i = t; i < 784; i += 256) {   // 2img x 14y x 14x x 2 half-rows
    int half = i & 1, xx = (i >> 1) % 14, y = ((i >> 1) / 14) % 14, img = i / 392;
    const int4 v = *(const int4*)(p1 + (((size_t)(bb * 2 + img) * 196 + y * 14 + xx) << 4) + half * 8);
    *(int4*)(smem + img * 7776 + ((y + 2) * 18 + (xx + 2)) * 24 + half * 8) = v;
  }
  __syncthreads();

  const int g = l >> 4;
  const int cil = (g & 1) * 8;
  const int tapadd = g >> 1;
  const int nmt = (w == 0) ? 7 : 6;   // M-tiles: w, w+4, ... < 25

  int abase[7];
#pragma unroll
  for (int jj = 0; jj < 7; ++jj) {
    int mt = w + jj * 4;
    int m = mt * 16 + (l & 15); if (m > 391) m = 391;
    int img = m / 196, pix = m % 196;
    int py = pix / 14, px = pix % 14;
    abase[jj] = img * 7776 + (py * 18 + px) * 24 + cil;
  }
  const float bias0 = b2[l & 15], bias1 = b2[16 + (l & 15)];
  f32x4 acc[7][2];
#pragma unroll
  for (int jj = 0; jj < 7; ++jj) {
    acc[jj][0] = (f32x4){bias0, bias0, bias0, bias0};
    acc[jj][1] = (f32x4){bias1, bias1, bias1, bias1};
  }
  const bf16x8* Bb = (const bf16x8*)Bp2;   // idx (c*2+nt)*64 + l
  bf16x8 b0 = Bb[l], b1 = Bb[64 + l];
  for (int c = 0; c < 13; ++c) {
    bf16x8 n0 = b0, n1 = b1;
    if (c < 12) { n0 = Bb[((c + 1) * 2) * 64 + l]; n1 = Bb[((c + 1) * 2 + 1) * 64 + l]; }
    int tp = 2 * c + tapadd; if (tp > 24) tp = 24;   // c=12 upper taps: B is 0
    int ky = tp / 5, kx = tp - ky * 5;
    int off = (ky * 18 + kx) * 24;
#pragma unroll
    for (int jj = 0; jj < 7; ++jj) {
      if (jj < nmt) {
        bf16x8 a = *(const bf16x8*)(smem + abase[jj] + off);
        acc[jj][0] = MFMA16(a, b0, acc[jj][0], 0, 0, 0);
        acc[jj][1] = MFMA16(a, b1, acc[jj][1], 0, 0, 0);
      }
    }
    b0 = n0; b1 = n1;
  }
  __syncthreads();   // all in_s reads done; alias as out buffer
#pragma unroll
  for (int jj = 0; jj < 7; ++jj) {
    if (jj < nmt) {
      int mt = w + jj * 4;
#pragma unroll
      for (int r = 0; r < 4; ++r) {
        int m = mt * 16 + (l >> 4) * 4 + r;
        if (m < 392) {
          int img = m / 196, pix = m % 196;
          smem[img * 6272 + (l & 15) * 196 + pix]        = f2b(fmaxf(acc[jj][0][r], 0.f));
          smem[img * 6272 + (16 + (l & 15)) * 196 + pix] = f2b(fmaxf(acc[jj][1][r], 0.f));
        }
      }
    }
  }
  __syncthreads();
  for (int i = t; i < 3136; i += 256) {   // pool 2x2 -> p2 [img][49][32]
    int co = i & 31, p = (i >> 5) % 49, img = i / 1568;
    int oy = p / 7, ox = p % 7;
    int base = img * 6272 + co * 196 + oy * 28 + ox * 2;
    u16 m0 = smem[base], m1 = smem[base + 1], m2 = smem[base + 14], m3 = smem[base + 15];
    u16 a = m0 > m1 ? m0 : m1, bq = m2 > m3 ? m2 : m3;   // nonneg bf16: uint max ok
    p2[(((size_t)(bb * 2 + img) * 49 + p) << 5) + co] = a > bq ? a : bq;
  }
}

// ---------------- conv3 MFMA: 4 img/block, M=196, N=64, K=800(25 chunks) ---
__global__ __launch_bounds__(256) void conv3_mfma(
    const u16* __restrict__ p2, const u16* __restrict__ Bp3,
    const float* __restrict__ b3, u16* __restrict__ p3) {
  __shared__ u16 smem[19360];   // in: 4 x [11][11][40ci-pad]; out aliases
  const int bb = blockIdx.x;
  const int t = threadIdx.x;
  const int w = t >> 6, l = t & 63;

  for (int i = t; i < 19360; i += 256) smem[i] = 0;
  __syncthreads();
  for (int i = t; i < 784; i += 256) {   // 4img x 7y x 7x x 4 ci-octs
    int oct = i & 3, xx = (i >> 2) % 7, y = ((i >> 2) / 7) % 7, img = i / 196;
    const int4 v = *(const int4*)(p2 + (((size_t)(bb * 4 + img) * 49 + y * 7 + xx) << 5) + oct * 8);
    *(int4*)(smem + img * 4840 + ((y + 2) * 11 + (xx + 2)) * 40 + oct * 8) = v;
  }
  __syncthreads();

  const int g = l >> 4;
  const int cil = g * 8;
  const int nmt = (w == 0) ? 4 : 3;   // M-tiles: w, w+4, ... < 13

  int abase[4];
#pragma unroll
  for (int jj = 0; jj < 4; ++jj) {
    int mt = w + jj * 4;
    int m = mt * 16 + (l & 15); if (m > 195) m = 195;
    int img = m / 49, pix = m % 49;
    int py = pix / 7, px = pix % 7;
    abase[jj] = img * 4840 + (py * 11 + px) * 40 + cil;
  }
  f32x4 acc[4][4];
#pragma unroll
  for (int q = 0; q < 4; ++q) {
    float bias = b3[q * 16 + (l & 15)];
#pragma unroll
    for (int jj = 0; jj < 4; ++jj)
      acc[jj][q] = (f32x4){bias, bias, bias, bias};
  }
  const bf16x8* Bb = (const bf16x8*)Bp3;   // idx (c*4+nt)*64 + l
  bf16x8 bfr[4];
#pragma unroll
  for (int q = 0; q < 4; ++q) bfr[q] = Bb[q * 64 + l];
  for (int c = 0; c < 25; ++c) {
    bf16x8 nb0 = bfr[0], nb1 = bfr[1], nb2 = bfr[2], nb3 = bfr[3];
    if (c < 24) {
      nb0 = Bb[((c + 1) * 4 + 0) * 64 + l];
      nb1 = Bb[((c + 1) * 4 + 1) * 64 + l];
      nb2 = Bb[((c + 1) * 4 + 2) * 64 + l];
      nb3 = Bb[((c + 1) * 4 + 3) * 64 + l];
    }
    int ky = c / 5, kx = c - ky * 5;
    int off = (ky * 11 + kx) * 40;
#pragma unroll
    for (int jj = 0; jj < 4; ++jj) {
      if (jj < nmt) {
        bf16x8 a = *(const bf16x8*)(smem + abase[jj] + off);
        acc[jj][0] = MFMA16(a, bfr[0], acc[jj][0], 0, 0, 0);
        acc[jj][1] = MFMA16(a, bfr[1], acc[jj][1], 0, 0, 0);
        acc[jj][2] = MFMA16(a, bfr[2], acc[jj][2], 0, 0, 0);
        acc[jj][3] = MFMA16(a, bfr[3], acc[jj][3], 0, 0, 0);
      }
    }
    bfr[0] = nb0; bfr[1] = nb1; bfr[2] = nb2; bfr[3] = nb3;
  }
  __syncthreads();   // alias smem as out buffer [img][64co][49]
#pragma unroll
  for (int jj = 0; jj < 4; ++jj) {
    if (jj < nmt) {
      int mt = w + jj * 4;
#pragma unroll
      for (int q = 0; q < 4; ++q)
#pragma unroll
        for (int r = 0; r < 4; ++r) {
          int m = mt * 16 + (l >> 4) * 4 + r;
          if (m < 196) {
            int img = m / 49, pix = m % 49;
            smem[img * 3136 + (q * 16 + (l & 15)) * 49 + pix] = f2b(fmaxf(acc[jj][q][r], 0.f));
          }
        }
    }
  }
  __syncthreads();
  for (int i = t; i < 4096; i += 256) {   // pool pad=1 -> p3 [img][co*16+p]
    int co = i & 63, p = (i >> 6) % 16, img = i >> 10;
    int oy = p >> 2, ox = p & 3;
    int y0 = oy ? 2 * oy - 1 : 0, y1 = 2 * oy;
    int x0 = ox ? 2 * ox - 1 : 0, x1 = 2 * ox;
    u16 mm = 0;   // relu'd values are >= 0
    for (int y = y0; y <= y1; ++y)
      for (int xx = x0; xx <= x1; ++xx) {
        u16 v = smem[img * 3136 + co * 49 + y * 7 + xx];
        if (v > mm) mm = v;
      }
    p3[(((size_t)(bb * 4 + img)) << 10) + co * 16 + p] = mm;
  }
}

// ---------------- fc1 MFMA: M=8192,N=256,K=1024; no LDS, prefetch ---------
__global__ __launch_bounds__(256) void fc1_mfma(
    const u16* __restrict__ p3, const u16* __restrict__ Bp1,
    const float* __restrict__ fb1, float* __restrict__ h4) {
  const int bid = blockIdx.x;
  const int mb = bid >> 1, nb = bid & 1;   // 128 x 2
  const int t = threadIdx.x;
  const int w = t >> 6, l = t & 63;
  const int g = l >> 4;

  const int mt0 = mb * 4 + (w >> 1) * 2;     // 2 M-tiles
  const int ntbase = nb * 8 + (w & 1) * 4;   // 4 N-tiles

  size_t arow0 = (size_t)(mt0 * 16 + (l & 15)) * 1024 + g * 8;
  size_t arow1 = arow0 + 16 * 1024;
  const bf16x8* Bb = (const bf16x8*)Bp1;     // idx (c*16+nt)*64 + l

  f32x4 acc[2][4];
#pragma unroll
  for (int i = 0; i < 2; ++i)
#pragma unroll
    for (int q = 0; q < 4; ++q) acc[i][q] = (f32x4){0.f, 0.f, 0.f, 0.f};

  bf16x8 a0 = *(const bf16x8*)(p3 + arow0);
  bf16x8 a1 = *(const bf16x8*)(p3 + arow1);
  bf16x8 bq0 = Bb[(ntbase + 0) * 64 + l], bq1 = Bb[(ntbase + 1) * 64 + l];
  bf16x8 bq2 = Bb[(ntbase + 2) * 64 + l], bq3 = Bb[(ntbase + 3) * 64 + l];

  for (int c = 0; c < 32; ++c) {
    bf16x8 na0 = a0, na1 = a1, nb0 = bq0, nb1 = bq1, nb2 = bq2, nb3 = bq3;
    if (c < 31) {
      na0 = *(const bf16x8*)(p3 + arow0 + (c + 1) * 32);
      na1 = *(const bf16x8*)(p3 + arow1 + (c + 1) * 32);
      nb0 = Bb[((c + 1) * 16 + ntbase + 0) * 64 + l];
      nb1 = Bb[((c + 1) * 16 + ntbase + 1) * 64 + l];
      nb2 = Bb[((c + 1) * 16 + ntbase + 2) * 64 + l];
      nb3 = Bb[((c + 1) * 16 + ntbase + 3) * 64 + l];
    }
    acc[0][0] = MFMA16(a0, bq0, acc[0][0], 0, 0, 0);
    acc[0][1] = MFMA16(a0, bq1, acc[0][1], 0, 0, 0);
    acc[0][2] = MFMA16(a0, bq2, acc[0][2], 0, 0, 0);
    acc[0][3] = MFMA16(a0, bq3, acc[0][3], 0, 0, 0);
    acc[1][0] = MFMA16(a1, bq0, acc[1][0], 0, 0, 0);
    acc[1][1] = MFMA16(a1, bq1, acc[1][1], 0, 0, 0);
    acc[1][2] = MFMA16(a1, bq2, acc[1][2], 0, 0, 0);
    acc[1][3] = MFMA16(a1, bq3, acc[1][3], 0, 0, 0);
    a0 = na0; a1 = na1; bq0 = nb0; bq1 = nb1; bq2 = nb2; bq3 = nb3;
  }
#pragma unroll
  for (int i = 0; i < 2; ++i) {
    int mrow = (mt0 + i) * 16 + g * 4;
#pragma unroll
    for (int q = 0; q < 4; ++q) {
      int col = (ntbase + q) * 16 + (l & 15);
      float bias = fb1[col];
#pragma unroll
      for (int r = 0; r < 4; ++r)
        h4[(size_t)(mrow + r) * 256 + col] = fmaxf(acc[i][q][r] + bias, 0.f);
    }
  }
}

// ---------------- fc2 + log_softmax (fp32), one wave per row --------------
__global__ __launch_bounds__(256) void fc2_lsm(
    const float* __restrict__ h4, const float* __restrict__ fw2,
    const float* __restrict__ fb2, float* __restrict__ out) {
  const int wave = threadIdx.x >> 6;
  const int lane = threadIdx.x & 63;
  const int b = blockIdx.x * 4 + wave;
  const float* h = h4 + (size_t)b * 256;
  float acc[10];
#pragma unroll
  for (int o = 0; o < 10; ++o) acc[o] = 0.f;
#pragma unroll
  for (int j = 0; j < 4; ++j) {
    const float a = h[lane + j * 64];
#pragma unroll
    for (int o = 0; o < 10; ++o)
      acc[o] = fmaf(a, fw2[o * 256 + lane + j * 64], acc[o]);
  }
#pragma unroll
  for (int o = 0; o < 10; ++o)
    for (int s = 32; s > 0; s >>= 1) acc[o] += __shfl_down(acc[o], s, 64);
  if (lane == 0) {
    float v[10], m = -1e30f;
#pragma unroll
    for (int o = 0; o < 10; ++o) { v[o] = acc[o] + fb2[o]; m = fmaxf(m, v[o]); }
    float s = 0.f;
#pragma unroll
    for (int o = 0; o < 10; ++o) s += expf(v[o] - m);
    const float lse = m + logf(s);
#pragma unroll
    for (int o = 0; o < 10; ++o) out[(size_t)b * 10 + o] = v[o] - lse;
  }
}

extern "C" void kernel_launch(void* const* d_in, const int* in_sizes, int n_in,
                              void* d_out, int out_size, void* d_ws, size_t ws_size,
                              hipStream_t stream) {
  const float* x   = (const float*)d_in[0];
  const float* w1  = (const float*)d_in[1];
  const float* b1  = (const float*)d_in[2];
  const float* w2  = (const float*)d_in[3];
  const float* b2  = (const float*)d_in[4];
  const float* w3  = (const float*)d_in[5];
  const float* b3  = (const float*)d_in[6];
  const float* fw1 = (const float*)d_in[7];
  const float* fb1 = (const float*)d_in[8];
  const float* fw2 = (const float*)d_in[9];
  const float* fb2 = (const float*)d_in[10];
  float* out = (float*)d_out;

  // Workspace byte layout (~103 MB total):
  char* W = (char*)d_ws;
  u16*   p1  = (u16*)(W);                    // 8192*3136*2   = 51,380,224
  u16*   p2  = (u16*)(W + 51380224);         // 8192*1568*2   = 25,690,112
  u16*   p3  = (u16*)(W + 77070336);         // 8192*1024*2   = 16,777,216
  float* h4  = (float*)(W + 93847552);       // 8192*256*4    =  8,388,608
  u16*   Bp2 = (u16*)(W + 102236160);        // 26,624
  u16*   Bp3 = (u16*)(W + 102262784);        // 102,400
  u16*   Bp1 = (u16*)(W + 102365184);        // 524,288
  u16*   Bp0 = (u16*)(W + 102889472);        // 143,360

  mega_pack <<<dim3(1556), dim3(256), 0, stream>>>(w2, w3, fw1, w1, Bp2, Bp3, Bp1, Bp0);
  conv1_mfma<<<dim3(7168), dim3(256), 0, stream>>>(x, Bp0, b1, p1);
  conv2_mfma<<<dim3(4096), dim3(256), 0, stream>>>(p1, Bp2, b2, p2);
  conv3_mfma<<<dim3(2048), dim3(256), 0, stream>>>(p2, Bp3, b3, p3);
  fc1_mfma<<<dim3(256), dim3(256), 0, stream>>>(p3, Bp1, fb1, h4);
  fc2_lsm<<<dim3(2048), dim3(256), 0, stream>>>(h4, fw2, fb2, out);
}

// Round 5
// 277.152 us; speedup vs baseline: 1.1495x; 1.1495x over previous
//
#include <hip/hip_runtime.h>
#include <hip/hip_bf16.h>
#include <math.h>

// ---------------------------------------------------------------------------
// LeNet forward, B=8192.  bf16 MFMA for conv1/conv2/conv3/fc1; fp32 fc2.
//  x[8192,1,28,28] -conv1(Toeplitz-MFMA)+pool-> p1 bf16 [img][196pix][16ci]
//  p1 -conv2+pool->  p2 bf16 [img][49pix][32ci]
//  p2 -conv3+pool->  p3 bf16 [img][1024] (k = co*16 + pix, ref flatten order)
//  p3 -fc1->         h4 f32  [8192][256]
//  h4 -fc2+lsm->     out f32 [8192][10]
// ---------------------------------------------------------------------------

typedef short bf16x8 __attribute__((ext_vector_type(8)));
typedef float f32x4 __attribute__((ext_vector_type(4)));
typedef unsigned short u16;
#define MFMA16 __builtin_amdgcn_mfma_f32_16x16x32_bf16

__device__ __forceinline__ u16 f2b(float f) {
  __hip_bfloat16 h = __float2bfloat16(f);
  return *reinterpret_cast<u16*>(&h);
}

// ---------------- one pack kernel for all four weight layouts --------------
// Bp2: [c13][nt2][lane64][j8]; k=tap*16+ci; tap=2c+(l>>5), ci=((l>>4)&1)*8+j
// Bp3: [c25][nt4][lane64][j8]; k=tap*32+ci; tap=c, ci=(l>>4)*8+j
// Bp1: [c32][nt16][lane64][j8]; k=c*32+(l>>4)*8+j
// Bp0 (conv1 Toeplitz): [c5=ky][px28][lane64][j8]; x'=(l>>4)*8+j, co=l&15;
//      val = w1[co][ky][x'-px] if 0<=x'-px<5 else 0
__global__ __launch_bounds__(256) void mega_pack(
    const float* __restrict__ w2, const float* __restrict__ w3,
    const float* __restrict__ fw1, const float* __restrict__ w1,
    u16* __restrict__ Bp2, u16* __restrict__ Bp3,
    u16* __restrict__ Bp1, u16* __restrict__ Bp0) {
  int gid = blockIdx.x * 256 + threadIdx.x;   // 398336 total (exact)
  if (gid < 13312) {
    int i = gid;
    int j = i & 7, lane = (i >> 3) & 63, nt = (i >> 9) & 1, c = i >> 10;
    int tap = 2 * c + (lane >> 5);
    int ci = ((lane >> 4) & 1) * 8 + j;
    int co = nt * 16 + (lane & 15);
    float v = (tap < 25) ? w2[co * 400 + ci * 25 + tap] : 0.f;
    Bp2[i] = f2b(v);
  } else if (gid < 64512) {
    int i = gid - 13312;
    int j = i & 7, lane = (i >> 3) & 63, nt = (i >> 9) & 3, c = i >> 11;
    int ci = (lane >> 4) * 8 + j;
    int co = nt * 16 + (lane & 15);
    Bp3[i] = f2b(w3[co * 800 + ci * 25 + c]);
  } else if (gid < 326656) {
    int i = gid - 64512;
    int j = i & 7, lane = (i >> 3) & 63, nt = (i >> 9) & 15, c = i >> 13;
    int k = c * 32 + (lane >> 4) * 8 + j;
    int col = nt * 16 + (lane & 15);
    Bp1[i] = f2b(fw1[col * 1024 + k]);
  } else {
    int i = gid - 326656;                     // 71680
    int j = i & 7, lane = (i >> 3) & 63, pc = i >> 9;
    int px = pc % 28, c = pc / 28;            // c = ky
    int co = lane & 15;
    int xp = (lane >> 4) * 8 + j;
    int kx = xp - px;
    float v = (kx >= 0 && kx < 5) ? w1[co * 25 + c * 5 + kx] : 0.f;
    Bp0[i] = f2b(v);
  }
}

// ---------------- conv1 via Toeplitz MFMA + in-register pool ---------------
// Block = 16 whole images, 448 thr = 7 waves.  Wave w owns px quad 4w..4w+3.
// M = 16*28 = 448 rows (img-major, py minor) -> 28 M-tiles.
// N-tile = one px (16 co).  K = 5 chunks of 32 (ky, x').
// B fragments (5x4 per wave) held in registers from L2-resident Bp0.
// A rows read from LDS padded images (stride 40 u16 = 20 words -> 2-way max).
// Pool in-register: px pairs inside quad, row pairs inside lane's 4 C-rows.
__global__ __launch_bounds__(448) void conv1_mfma(
    const float* __restrict__ x, const u16* __restrict__ Bp0,
    const float* __restrict__ b1, u16* __restrict__ p1) {
  __shared__ u16 img_s[16 * 1280];   // 16 img x [32 rows][40 cols], 40 KB
  const int imgG = blockIdx.x;       // 512 blocks x 16 images
  const int t = threadIdx.x;
  const int w = t >> 6, l = t & 63;
  const int co = l & 15, g = l >> 4;
  const int p0 = w * 4;              // px quad base

  bf16x8 Bfr[5][4];
#pragma unroll
  for (int c = 0; c < 5; ++c)
#pragma unroll
    for (int q = 0; q < 4; ++q)
      Bfr[c][q] = *(const bf16x8*)(Bp0 + ((size_t)(c * 28 + p0 + q) << 9) + l * 8);

  const int4 z4 = make_int4(0, 0, 0, 0);
  for (int i = t; i < 2560; i += 448) ((int4*)img_s)[i] = z4;
  __syncthreads();
  const float2* xg = (const float2*)(x + (size_t)imgG * 16 * 784);
  for (int i = t; i < 6272; i += 448) {
    int p = i / 14, xc = (i % 14) * 2;
    float2 v = xg[i];
    int img = p / 28, y = p % 28;
    unsigned pk = (unsigned)f2b(v.x) | ((unsigned)f2b(v.y) << 16);
    *(unsigned*)(img_s + img * 1280 + (y + 2) * 40 + xc + 2) = pk;
  }
  __syncthreads();

  const float bias = b1[co];
  const int pxp0 = p0 >> 1;
  for (int mt = 0; mt < 28; ++mt) {
    int m = mt * 16 + co;            // this lane's A row
    int imgA = m / 28, py = m - imgA * 28;
    const u16* ap = img_s + imgA * 1280 + py * 40 + g * 8;
    f32x4 a0 = (f32x4){bias, bias, bias, bias};
    f32x4 a1 = a0, a2 = a0, a3 = a0;
#pragma unroll
    for (int c = 0; c < 5; ++c) {
      bf16x8 av = *(const bf16x8*)(ap + c * 40);
      a0 = MFMA16(av, Bfr[c][0], a0, 0, 0, 0);
      a1 = MFMA16(av, Bfr[c][1], a1, 0, 0, 0);
      a2 = MFMA16(av, Bfr[c][2], a2, 0, 0, 0);
      a3 = MFMA16(av, Bfr[c][3], a3, 0, 0, 0);
    }
    int m0 = mt * 16 + g * 4;        // lane's first C row
    int imgC = m0 / 28, py0 = m0 - imgC * 28;   // py0 multiple of 4
    size_t base = ((size_t)((imgG * 16 + imgC) * 196)) << 4;
    int pyp0 = py0 >> 1;
#pragma unroll
    for (int h = 0; h < 2; ++h) {
      float vA = fmaxf(fmaxf(a0[2 * h], a0[2 * h + 1]),
                       fmaxf(a1[2 * h], a1[2 * h + 1]));
      float vB = fmaxf(fmaxf(a2[2 * h], a2[2 * h + 1]),
                       fmaxf(a3[2 * h], a3[2 * h + 1]));
      p1[base + (((size_t)(pyp0 + h) * 14 + pxp0) << 4) + co]     = f2b(fmaxf(vA, 0.f));
      p1[base + (((size_t)(pyp0 + h) * 14 + pxp0 + 1) << 4) + co] = f2b(fmaxf(vB, 0.f));
    }
  }
}

// ---------------- conv2 MFMA: 2 img/block, M=392, N=32, K=400(13 chunks) ---
__global__ __launch_bounds__(256) void conv2_mfma(
    const u16* __restrict__ p1, const u16* __restrict__ Bp2,
    const float* __restrict__ b2, u16* __restrict__ p2) {
  __shared__ u16 smem[15552];   // in: 2 x [18][18][24ci-pad] ; out aliases
  const int bb = blockIdx.x;
  const int t = threadIdx.x;
  const int w = t >> 6, l = t & 63;

  for (int i = t; i < 15552; i += 256) smem[i] = 0;
  __syncthreads();
  for (int i = t; i < 784; i += 256) {   // 2img x 14y x 14x x 2 half-rows
    int half = i & 1, xx = (i >> 1) % 14, y = ((i >> 1) / 14) % 14, img = i / 392;
    const int4 v = *(const int4*)(p1 + (((size_t)(bb * 2 + img) * 196 + y * 14 + xx) << 4) + half * 8);
    *(int4*)(smem + img * 7776 + ((y + 2) * 18 + (xx + 2)) * 24 + half * 8) = v;
  }
  __syncthreads();

  const int g = l >> 4;
  const int cil = (g & 1) * 8;
  const int tapadd = g >> 1;
  const int nmt = (w == 0) ? 7 : 6;   // M-tiles: w, w+4, ... < 25

  int abase[7];
#pragma unroll
  for (int jj = 0; jj < 7; ++jj) {
    int mt = w + jj * 4;
    int m = mt * 16 + (l & 15); if (m > 391) m = 391;
    int img = m / 196, pix = m % 196;
    int py = pix / 14, px = pix % 14;
    abase[jj] = img * 7776 + (py * 18 + px) * 24 + cil;
  }
  const float bias0 = b2[l & 15], bias1 = b2[16 + (l & 15)];
  f32x4 acc[7][2];
#pragma unroll
  for (int jj = 0; jj < 7; ++jj) {
    acc[jj][0] = (f32x4){bias0, bias0, bias0, bias0};
    acc[jj][1] = (f32x4){bias1, bias1, bias1, bias1};
  }
  const bf16x8* Bb = (const bf16x8*)Bp2;   // idx (c*2+nt)*64 + l
  bf16x8 b0 = Bb[l], b1 = Bb[64 + l];
  for (int c = 0; c < 13; ++c) {
    bf16x8 n0 = b0, n1 = b1;
    if (c < 12) { n0 = Bb[((c + 1) * 2) * 64 + l]; n1 = Bb[((c + 1) * 2 + 1) * 64 + l]; }
    int tp = 2 * c + tapadd; if (tp > 24) tp = 24;   // c=12 upper taps: B is 0
    int ky = tp / 5, kx = tp - ky * 5;
    int off = (ky * 18 + kx) * 24;
#pragma unroll
    for (int jj = 0; jj < 7; ++jj) {
      if (jj < nmt) {
        bf16x8 a = *(const bf16x8*)(smem + abase[jj] + off);
        acc[jj][0] = MFMA16(a, b0, acc[jj][0], 0, 0, 0);
        acc[jj][1] = MFMA16(a, b1, acc[jj][1], 0, 0, 0);
      }
    }
    b0 = n0; b1 = n1;
  }
  __syncthreads();   // all in_s reads done; alias as out buffer
#pragma unroll
  for (int jj = 0; jj < 7; ++jj) {
    if (jj < nmt) {
      int mt = w + jj * 4;
#pragma unroll
      for (int r = 0; r < 4; ++r) {
        int m = mt * 16 + (l >> 4) * 4 + r;
        if (m < 392) {
          int img = m / 196, pix = m % 196;
          smem[img * 6272 + (l & 15) * 196 + pix]        = f2b(fmaxf(acc[jj][0][r], 0.f));
          smem[img * 6272 + (16 + (l & 15)) * 196 + pix] = f2b(fmaxf(acc[jj][1][r], 0.f));
        }
      }
    }
  }
  __syncthreads();
  for (int i = t; i < 3136; i += 256) {   // pool 2x2 -> p2 [img][49][32]
    int co = i & 31, p = (i >> 5) % 49, img = i / 1568;
    int oy = p / 7, ox = p % 7;
    int base = img * 6272 + co * 196 + oy * 28 + ox * 2;
    u16 m0 = smem[base], m1 = smem[base + 1], m2 = smem[base + 14], m3 = smem[base + 15];
    u16 a = m0 > m1 ? m0 : m1, bq = m2 > m3 ? m2 : m3;   // nonneg bf16: uint max ok
    p2[(((size_t)(bb * 2 + img) * 49 + p) << 5) + co] = a > bq ? a : bq;
  }
}

// ---------------- conv3 MFMA: 4 img/block, M=196, N=64, K=800(25 chunks) ---
__global__ __launch_bounds__(256) void conv3_mfma(
    const u16* __restrict__ p2, const u16* __restrict__ Bp3,
    const float* __restrict__ b3, u16* __restrict__ p3) {
  __shared__ u16 smem[19360];   // in: 4 x [11][11][40ci-pad]; out aliases
  const int bb = blockIdx.x;
  const int t = threadIdx.x;
  const int w = t >> 6, l = t & 63;

  for (int i = t; i < 19360; i += 256) smem[i] = 0;
  __syncthreads();
  for (int i = t; i < 784; i += 256) {   // 4img x 7y x 7x x 4 ci-octs
    int oct = i & 3, xx = (i >> 2) % 7, y = ((i >> 2) / 7) % 7, img = i / 196;
    const int4 v = *(const int4*)(p2 + (((size_t)(bb * 4 + img) * 49 + y * 7 + xx) << 5) + oct * 8);
    *(int4*)(smem + img * 4840 + ((y + 2) * 11 + (xx + 2)) * 40 + oct * 8) = v;
  }
  __syncthreads();

  const int g = l >> 4;
  const int cil = g * 8;
  const int nmt = (w == 0) ? 4 : 3;   // M-tiles: w, w+4, ... < 13

  int abase[4];
#pragma unroll
  for (int jj = 0; jj < 4; ++jj) {
    int mt = w + jj * 4;
    int m = mt * 16 + (l & 15); if (m > 195) m = 195;
    int img = m / 49, pix = m % 49;
    int py = pix / 7, px = pix % 7;
    abase[jj] = img * 4840 + (py * 11 + px) * 40 + cil;
  }
  f32x4 acc[4][4];
#pragma unroll
  for (int q = 0; q < 4; ++q) {
    float bias = b3[q * 16 + (l & 15)];
#pragma unroll
    for (int jj = 0; jj < 4; ++jj)
      acc[jj][q] = (f32x4){bias, bias, bias, bias};
  }
  const bf16x8* Bb = (const bf16x8*)Bp3;   // idx (c*4+nt)*64 + l
  bf16x8 bfr[4];
#pragma unroll
  for (int q = 0; q < 4; ++q) bfr[q] = Bb[q * 64 + l];
  for (int c = 0; c < 25; ++c) {
    bf16x8 nb0 = bfr[0], nb1 = bfr[1], nb2 = bfr[2], nb3 = bfr[3];
    if (c < 24) {
      nb0 = Bb[((c + 1) * 4 + 0) * 64 + l];
      nb1 = Bb[((c + 1) * 4 + 1) * 64 + l];
      nb2 = Bb[((c + 1) * 4 + 2) * 64 + l];
      nb3 = Bb[((c + 1) * 4 + 3) * 64 + l];
    }
    int ky = c / 5, kx = c - ky * 5;
    int off = (ky * 11 + kx) * 40;
#pragma unroll
    for (int jj = 0; jj < 4; ++jj) {
      if (jj < nmt) {
        bf16x8 a = *(const bf16x8*)(smem + abase[jj] + off);
        acc[jj][0] = MFMA16(a, bfr[0], acc[jj][0], 0, 0, 0);
        acc[jj][1] = MFMA16(a, bfr[1], acc[jj][1], 0, 0, 0);
        acc[jj][2] = MFMA16(a, bfr[2], acc[jj][2], 0, 0, 0);
        acc[jj][3] = MFMA16(a, bfr[3], acc[jj][3], 0, 0, 0);
      }
    }
    bfr[0] = nb0; bfr[1] = nb1; bfr[2] = nb2; bfr[3] = nb3;
  }
  __syncthreads();   // alias smem as out buffer [img][64co][49]
#pragma unroll
  for (int jj = 0; jj < 4; ++jj) {
    if (jj < nmt) {
      int mt = w + jj * 4;
#pragma unroll
      for (int q = 0; q < 4; ++q)
#pragma unroll
        for (int r = 0; r < 4; ++r) {
          int m = mt * 16 + (l >> 4) * 4 + r;
          if (m < 196) {
            int img = m / 49, pix = m % 49;
            smem[img * 3136 + (q * 16 + (l & 15)) * 49 + pix] = f2b(fmaxf(acc[jj][q][r], 0.f));
          }
        }
    }
  }
  __syncthreads();
  for (int i = t; i < 4096; i += 256) {   // pool pad=1 -> p3 [img][co*16+p]
    int co = i & 63, p = (i >> 6) % 16, img = i >> 10;
    int oy = p >> 2, ox = p & 3;
    int y0 = oy ? 2 * oy - 1 : 0, y1 = 2 * oy;
    int x0 = ox ? 2 * ox - 1 : 0, x1 = 2 * ox;
    u16 mm = 0;   // relu'd values are >= 0
    for (int y = y0; y <= y1; ++y)
      for (int xx = x0; xx <= x1; ++xx) {
        u16 v = smem[img * 3136 + co * 49 + y * 7 + xx];
        if (v > mm) mm = v;
      }
    p3[(((size_t)(bb * 4 + img)) << 10) + co * 16 + p] = mm;
  }
}

// ---------------- fc1 MFMA: M=8192,N=256,K=1024; no LDS, prefetch ---------
__global__ __launch_bounds__(256) void fc1_mfma(
    const u16* __restrict__ p3, const u16* __restrict__ Bp1,
    const float* __restrict__ fb1, float* __restrict__ h4) {
  const int bid = blockIdx.x;
  const int mb = bid >> 1, nb = bid & 1;   // 128 x 2
  const int t = threadIdx.x;
  const int w = t >> 6, l = t & 63;
  const int g = l >> 4;

  const int mt0 = mb * 4 + (w >> 1) * 2;     // 2 M-tiles
  const int ntbase = nb * 8 + (w & 1) * 4;   // 4 N-tiles

  size_t arow0 = (size_t)(mt0 * 16 + (l & 15)) * 1024 + g * 8;
  size_t arow1 = arow0 + 16 * 1024;
  const bf16x8* Bb = (const bf16x8*)Bp1;     // idx (c*16+nt)*64 + l

  f32x4 acc[2][4];
#pragma unroll
  for (int i = 0; i < 2; ++i)
#pragma unroll
    for (int q = 0; q < 4; ++q) acc[i][q] = (f32x4){0.f, 0.f, 0.f, 0.f};

  bf16x8 a0 = *(const bf16x8*)(p3 + arow0);
  bf16x8 a1 = *(const bf16x8*)(p3 + arow1);
  bf16x8 bq0 = Bb[(ntbase + 0) * 64 + l], bq1 = Bb[(ntbase + 1) * 64 + l];
  bf16x8 bq2 = Bb[(ntbase + 2) * 64 + l], bq3 = Bb[(ntbase + 3) * 64 + l];

  for (int c = 0; c < 32; ++c) {
    bf16x8 na0 = a0, na1 = a1, nb0 = bq0, nb1 = bq1, nb2 = bq2, nb3 = bq3;
    if (c < 31) {
      na0 = *(const bf16x8*)(p3 + arow0 + (c + 1) * 32);
      na1 = *(const bf16x8*)(p3 + arow1 + (c + 1) * 32);
      nb0 = Bb[((c + 1) * 16 + ntbase + 0) * 64 + l];
      nb1 = Bb[((c + 1) * 16 + ntbase + 1) * 64 + l];
      nb2 = Bb[((c + 1) * 16 + ntbase + 2) * 64 + l];
      nb3 = Bb[((c + 1) * 16 + ntbase + 3) * 64 + l];
    }
    acc[0][0] = MFMA16(a0, bq0, acc[0][0], 0, 0, 0);
    acc[0][1] = MFMA16(a0, bq1, acc[0][1], 0, 0, 0);
    acc[0][2] = MFMA16(a0, bq2, acc[0][2], 0, 0, 0);
    acc[0][3] = MFMA16(a0, bq3, acc[0][3], 0, 0, 0);
    acc[1][0] = MFMA16(a1, bq0, acc[1][0], 0, 0, 0);
    acc[1][1] = MFMA16(a1, bq1, acc[1][1], 0, 0, 0);
    acc[1][2] = MFMA16(a1, bq2, acc[1][2], 0, 0, 0);
    acc[1][3] = MFMA16(a1, bq3, acc[1][3], 0, 0, 0);
    a0 = na0; a1 = na1; bq0 = nb0; bq1 = nb1; bq2 = nb2; bq3 = nb3;
  }
#pragma unroll
  for (int i = 0; i < 2; ++i) {
    int mrow = (mt0 + i) * 16 + g * 4;
#pragma unroll
    for (int q = 0; q < 4; ++q) {
      int col = (ntbase + q) * 16 + (l & 15);
      float bias = fb1[col];
#pragma unroll
      for (int r = 0; r < 4; ++r)
        h4[(size_t)(mrow + r) * 256 + col] = fmaxf(acc[i][q][r] + bias, 0.f);
    }
  }
}

// ---------------- fc2 + log_softmax (fp32), one wave per row --------------
__global__ __launch_bounds__(256) void fc2_lsm(
    const float* __restrict__ h4, const float* __restrict__ fw2,
    const float* __restrict__ fb2, float* __restrict__ out) {
  const int wave = threadIdx.x >> 6;
  const int lane = threadIdx.x & 63;
  const int b = blockIdx.x * 4 + wave;
  const float* h = h4 + (size_t)b * 256;
  float acc[10];
#pragma unroll
  for (int o = 0; o < 10; ++o) acc[o] = 0.f;
#pragma unroll
  for (int j = 0; j < 4; ++j) {
    const float a = h[lane + j * 64];
#pragma unroll
    for (int o = 0; o < 10; ++o)
      acc[o] = fmaf(a, fw2[o * 256 + lane + j * 64], acc[o]);
  }
#pragma unroll
  for (int o = 0; o < 10; ++o)
    for (int s = 32; s > 0; s >>= 1) acc[o] += __shfl_down(acc[o], s, 64);
  if (lane == 0) {
    float v[10], m = -1e30f;
#pragma unroll
    for (int o = 0; o < 10; ++o) { v[o] = acc[o] + fb2[o]; m = fmaxf(m, v[o]); }
    float s = 0.f;
#pragma unroll
    for (int o = 0; o < 10; ++o) s += expf(v[o] - m);
    const float lse = m + logf(s);
#pragma unroll
    for (int o = 0; o < 10; ++o) out[(size_t)b * 10 + o] = v[o] - lse;
  }
}

extern "C" void kernel_launch(void* const* d_in, const int* in_sizes, int n_in,
                              void* d_out, int out_size, void* d_ws, size_t ws_size,
                              hipStream_t stream) {
  const float* x   = (const float*)d_in[0];
  const float* w1  = (const float*)d_in[1];
  const float* b1  = (const float*)d_in[2];
  const float* w2  = (const float*)d_in[3];
  const float* b2  = (const float*)d_in[4];
  const float* w3  = (const float*)d_in[5];
  const float* b3  = (const float*)d_in[6];
  const float* fw1 = (const float*)d_in[7];
  const float* fb1 = (const float*)d_in[8];
  const float* fw2 = (const float*)d_in[9];
  const float* fb2 = (const float*)d_in[10];
  float* out = (float*)d_out;

  // Workspace byte layout (~103 MB total):
  char* W = (char*)d_ws;
  u16*   p1  = (u16*)(W);                    // 8192*3136*2   = 51,380,224
  u16*   p2  = (u16*)(W + 51380224);         // 8192*1568*2   = 25,690,112
  u16*   p3  = (u16*)(W + 77070336);         // 8192*1024*2   = 16,777,216
  float* h4  = (float*)(W + 93847552);       // 8192*256*4    =  8,388,608
  u16*   Bp2 = (u16*)(W + 102236160);        // 26,624
  u16*   Bp3 = (u16*)(W + 102262784);        // 102,400
  u16*   Bp1 = (u16*)(W + 102365184);        // 524,288
  u16*   Bp0 = (u16*)(W + 102889472);        // 143,360

  mega_pack <<<dim3(1556), dim3(256), 0, stream>>>(w2, w3, fw1, w1, Bp2, Bp3, Bp1, Bp0);
  conv1_mfma<<<dim3(512),  dim3(448), 0, stream>>>(x, Bp0, b1, p1);
  conv2_mfma<<<dim3(4096), dim3(256), 0, stream>>>(p1, Bp2, b2, p2);
  conv3_mfma<<<dim3(2048), dim3(256), 0, stream>>>(p2, Bp3, b3, p3);
  fc1_mfma<<<dim3(256), dim3(256), 0, stream>>>(p3, Bp1, fb1, h4);
  fc2_lsm<<<dim3(2048), dim3(256), 0, stream>>>(h4, fw2, fb2, out);
}

// Round 8
// 241.748 us; speedup vs baseline: 1.3178x; 1.1465x over previous
//
#include <hip/hip_runtime.h>
#include <hip/hip_bf16.h>
#include <math.h>

// ---------------------------------------------------------------------------
// LeNet forward, B=8192.  bf16 MFMA for conv1/conv2/conv3/fc1; fp32 fc2.
//  x[8192,1,28,28] -conv1(Toeplitz-MFMA)+pool-> p1 bf16 [img][196pix][16ci]
//  p1 -conv2+pool->  p2 bf16 [img][49pix][32ci]
//  p2 -conv3+pool->  p3 bf16 [img][1024] (k = co*16 + pix, ref flatten order)
//  p3 -fc1->         h4 f32  [8192][256]
//  h4 -fc2+lsm->     out f32 [8192][10]
// conv2/conv3: M ordered pool-window-major so each lane's 4 C-rows = one 2x2
// window -> pool+relu in registers, direct global store (no LDS round-trip).
// conv3 pool(pad=1) done on zero-padded 8x8 grid (exact: inputs >= 0).
// NOTE abase must NOT re-add the +2 pad offset (it cancels: output(py,px)
// needs staged row (py+ky), since input is staged at +2).  [r6 fix]
// ---------------------------------------------------------------------------

typedef short bf16x8 __attribute__((ext_vector_type(8)));
typedef float f32x4 __attribute__((ext_vector_type(4)));
typedef unsigned short u16;
#define MFMA16 __builtin_amdgcn_mfma_f32_16x16x32_bf16

__device__ __forceinline__ u16 f2b(float f) {
  __hip_bfloat16 h = __float2bfloat16(f);
  return *reinterpret_cast<u16*>(&h);
}

// ---------------- one pack kernel for all four weight layouts --------------
// Bp2: [c13][nt2][lane64][j8]; k=tap*16+ci; tap=2c+(l>>5), ci=((l>>4)&1)*8+j
// Bp3: [c25][nt4][lane64][j8]; k=tap*32+ci; tap=c, ci=(l>>4)*8+j
// Bp1: [c32][nt16][lane64][j8]; k=c*32+(l>>4)*8+j
// Bp0 (conv1 Toeplitz): [c5=ky][px28][lane64][j8]; x'=(l>>4)*8+j, co=l&15;
//      val = w1[co][ky][x'-px] if 0<=x'-px<5 else 0
__global__ __launch_bounds__(256) void mega_pack(
    const float* __restrict__ w2, const float* __restrict__ w3,
    const float* __restrict__ fw1, const float* __restrict__ w1,
    u16* __restrict__ Bp2, u16* __restrict__ Bp3,
    u16* __restrict__ Bp1, u16* __restrict__ Bp0) {
  int gid = blockIdx.x * 256 + threadIdx.x;   // 398336 total (exact)
  if (gid < 13312) {
    int i = gid;
    int j = i & 7, lane = (i >> 3) & 63, nt = (i >> 9) & 1, c = i >> 10;
    int tap = 2 * c + (lane >> 5);
    int ci = ((lane >> 4) & 1) * 8 + j;
    int co = nt * 16 + (lane & 15);
    float v = (tap < 25) ? w2[co * 400 + ci * 25 + tap] : 0.f;
    Bp2[i] = f2b(v);
  } else if (gid < 64512) {
    int i = gid - 13312;
    int j = i & 7, lane = (i >> 3) & 63, nt = (i >> 9) & 3, c = i >> 11;
    int ci = (lane >> 4) * 8 + j;
    int co = nt * 16 + (lane & 15);
    Bp3[i] = f2b(w3[co * 800 + ci * 25 + c]);
  } else if (gid < 326656) {
    int i = gid - 64512;
    int j = i & 7, lane = (i >> 3) & 63, nt = (i >> 9) & 15, c = i >> 13;
    int k = c * 32 + (lane >> 4) * 8 + j;
    int col = nt * 16 + (lane & 15);
    Bp1[i] = f2b(fw1[col * 1024 + k]);
  } else {
    int i = gid - 326656;                     // 71680
    int j = i & 7, lane = (i >> 3) & 63, pc = i >> 9;
    int px = pc % 28, c = pc / 28;            // c = ky
    int co = lane & 15;
    int xp = (lane >> 4) * 8 + j;
    int kx = xp - px;
    float v = (kx >= 0 && kx < 5) ? w1[co * 25 + c * 5 + kx] : 0.f;
    Bp0[i] = f2b(v);
  }
}

// ---------------- conv1 via Toeplitz MFMA + in-register pool ---------------
__global__ __launch_bounds__(448) void conv1_mfma(
    const float* __restrict__ x, const u16* __restrict__ Bp0,
    const float* __restrict__ b1, u16* __restrict__ p1) {
  __shared__ u16 img_s[16 * 1280];   // 16 img x [32 rows][40 cols], 40 KB
  const int imgG = blockIdx.x;       // 512 blocks x 16 images
  const int t = threadIdx.x;
  const int w = t >> 6, l = t & 63;
  const int co = l & 15, g = l >> 4;
  const int p0 = w * 4;              // px quad base

  bf16x8 Bfr[5][4];
#pragma unroll
  for (int c = 0; c < 5; ++c)
#pragma unroll
    for (int q = 0; q < 4; ++q)
      Bfr[c][q] = *(const bf16x8*)(Bp0 + ((size_t)(c * 28 + p0 + q) << 9) + l * 8);

  const int4 z4 = make_int4(0, 0, 0, 0);
  for (int i = t; i < 2560; i += 448) ((int4*)img_s)[i] = z4;
  __syncthreads();
  const float2* xg = (const float2*)(x + (size_t)imgG * 16 * 784);
  for (int i = t; i < 6272; i += 448) {
    int p = i / 14, xc = (i % 14) * 2;
    float2 v = xg[i];
    int img = p / 28, y = p % 28;
    unsigned pk = (unsigned)f2b(v.x) | ((unsigned)f2b(v.y) << 16);
    *(unsigned*)(img_s + img * 1280 + (y + 2) * 40 + xc + 2) = pk;
  }
  __syncthreads();

  const float bias = b1[co];
  const int pxp0 = p0 >> 1;
  for (int mt = 0; mt < 28; ++mt) {
    int m = mt * 16 + co;            // this lane's A row
    int imgA = m / 28, py = m - imgA * 28;
    const u16* ap = img_s + imgA * 1280 + py * 40 + g * 8;
    f32x4 a0 = (f32x4){bias, bias, bias, bias};
    f32x4 a1 = a0, a2 = a0, a3 = a0;
#pragma unroll
    for (int c = 0; c < 5; ++c) {
      bf16x8 av = *(const bf16x8*)(ap + c * 40);
      a0 = MFMA16(av, Bfr[c][0], a0, 0, 0, 0);
      a1 = MFMA16(av, Bfr[c][1], a1, 0, 0, 0);
      a2 = MFMA16(av, Bfr[c][2], a2, 0, 0, 0);
      a3 = MFMA16(av, Bfr[c][3], a3, 0, 0, 0);
    }
    int m0 = mt * 16 + g * 4;        // lane's first C row
    int imgC = m0 / 28, py0 = m0 - imgC * 28;   // py0 multiple of 4
    size_t base = ((size_t)((imgG * 16 + imgC) * 196)) << 4;
    int pyp0 = py0 >> 1;
#pragma unroll
    for (int h = 0; h < 2; ++h) {
      float vA = fmaxf(fmaxf(a0[2 * h], a0[2 * h + 1]),
                       fmaxf(a1[2 * h], a1[2 * h + 1]));
      float vB = fmaxf(fmaxf(a2[2 * h], a2[2 * h + 1]),
                       fmaxf(a3[2 * h], a3[2 * h + 1]));
      p1[base + (((size_t)(pyp0 + h) * 14 + pxp0) << 4) + co]     = f2b(fmaxf(vA, 0.f));
      p1[base + (((size_t)(pyp0 + h) * 14 + pxp0 + 1) << 4) + co] = f2b(fmaxf(vB, 0.f));
    }
  }
}

// ---------------- conv2 MFMA: 2 img/block, window-major M, in-reg pool -----
// M = 392: m = img*196 + wl*4 + e, e=dy*2+dx of the 2x2 pool window wl.
// N = 32 (2 tiles), K = 400 (13 chunks: 2 taps x 16 ci).
__global__ __launch_bounds__(256) void conv2_mfma(
    const u16* __restrict__ p1, const u16* __restrict__ Bp2,
    const float* __restrict__ b2, u16* __restrict__ p2) {
  __shared__ u16 smem[15552];   // 2 x [18][18][24ci-pad]
  const int bb = blockIdx.x;
  const int t = threadIdx.x;
  const int w = t >> 6, l = t & 63;

  const int4 z4 = make_int4(0, 0, 0, 0);
  for (int i = t; i < 1944; i += 256) ((int4*)smem)[i] = z4;
  __syncthreads();
  for (int i = t; i < 784; i += 256) {   // 2img x 14y x 14x x 2 half-rows
    int half = i & 1, xx = (i >> 1) % 14, y = ((i >> 1) / 14) % 14, img = i / 392;
    const int4 v = *(const int4*)(p1 + (((size_t)(bb * 2 + img) * 196 + y * 14 + xx) << 4) + half * 8);
    *(int4*)(smem + img * 7776 + ((y + 2) * 18 + (xx + 2)) * 24 + half * 8) = v;
  }
  __syncthreads();

  const int g = l >> 4;
  const int cil = (g & 1) * 8;
  const int tapadd = g >> 1;
  const int col = l & 15;
  const int nmt = (w == 0) ? 7 : 6;   // M-tiles: w, w+4, ... (tile 24 on w=0)

  int abase[7];
#pragma unroll
  for (int jj = 0; jj < 7; ++jj) {
    int m = (w + jj * 4) * 16 + col; if (m > 391) m = 391;
    int img = m / 196, rel = m - img * 196;
    int wl = rel >> 2, e = rel & 3;
    int oy = wl / 7, ox = wl - oy * 7;
    int py = 2 * oy + (e >> 1), px = 2 * ox + (e & 1);
    abase[jj] = img * 7776 + (py * 18 + px) * 24 + cil;   // no +2: cancels
  }
  const float bias0 = b2[col], bias1 = b2[16 + col];
  f32x4 acc[7][2];
#pragma unroll
  for (int jj = 0; jj < 7; ++jj) {
    acc[jj][0] = (f32x4){bias0, bias0, bias0, bias0};
    acc[jj][1] = (f32x4){bias1, bias1, bias1, bias1};
  }
  const bf16x8* Bb = (const bf16x8*)Bp2;   // idx (c*2+nt)*64 + l
  bf16x8 b0 = Bb[l], b1 = Bb[64 + l];
  for (int c = 0; c < 13; ++c) {
    bf16x8 n0 = b0, n1 = b1;
    if (c < 12) { n0 = Bb[((c + 1) * 2) * 64 + l]; n1 = Bb[((c + 1) * 2 + 1) * 64 + l]; }
    int tp = 2 * c + tapadd; if (tp > 24) tp = 24;   // c=12 upper tap: B is 0
    int ky = tp / 5, kx = tp - ky * 5;
    int off = (ky * 18 + kx) * 24;
#pragma unroll
    for (int jj = 0; jj < 7; ++jj) {
      if (jj < nmt) {
        bf16x8 a = *(const bf16x8*)(smem + abase[jj] + off);
        acc[jj][0] = MFMA16(a, b0, acc[jj][0], 0, 0, 0);
        acc[jj][1] = MFMA16(a, b1, acc[jj][1], 0, 0, 0);
      }
    }
    b0 = n0; b1 = n1;
  }
  // pool+relu in registers: lane's 4 C-rows (m0..m0+3) = one window.
#pragma unroll
  for (int jj = 0; jj < 7; ++jj) {
    if (jj < nmt) {
      int m0 = (w + jj * 4) * 16 + g * 4;
      if (m0 < 392) {
        int img = m0 / 196, rel = m0 - img * 196;
        int wl = rel >> 2;
        float v0 = fmaxf(fmaxf(acc[jj][0][0], acc[jj][0][1]),
                         fmaxf(acc[jj][0][2], acc[jj][0][3]));
        float v1 = fmaxf(fmaxf(acc[jj][1][0], acc[jj][1][1]),
                         fmaxf(acc[jj][1][2], acc[jj][1][3]));
        size_t base = (((size_t)(bb * 2 + img) * 49 + wl) << 5);
        p2[base + col]      = f2b(fmaxf(v0, 0.f));
        p2[base + 16 + col] = f2b(fmaxf(v1, 0.f));
      }
    }
  }
}

// ---------------- conv3 MFMA: 4 img/block, 8x8-padded window-major ---------
// Pool(pad=1) on zero-padded 8x8 grid (exact for relu'd inputs >= 0).
// M = 4*64 = 256 (16 tiles): m = img*64 + wa*4 + e; wa = oy*4+ox.
// N = 64 (4 tiles), K = 800 (25 chunks x 32 ci).
__global__ __launch_bounds__(256) void conv3_mfma(
    const u16* __restrict__ p2, const u16* __restrict__ Bp3,
    const float* __restrict__ b3, u16* __restrict__ p3) {
  __shared__ u16 smem[19360];   // 4 x [11][11][40ci-pad]
  const int bb = blockIdx.x;
  const int t = threadIdx.x;
  const int w = t >> 6, l = t & 63;

  const int4 z4 = make_int4(0, 0, 0, 0);
  for (int i = t; i < 2420; i += 256) ((int4*)smem)[i] = z4;
  __syncthreads();
  for (int i = t; i < 784; i += 256) {   // 4img x 7y x 7x x 4 ci-octs
    int oct = i & 3, xx = (i >> 2) % 7, y = ((i >> 2) / 7) % 7, img = i / 196;
    const int4 v = *(const int4*)(p2 + (((size_t)(bb * 4 + img) * 49 + y * 7 + xx) << 5) + oct * 8);
    *(int4*)(smem + img * 4840 + ((y + 2) * 11 + (xx + 2)) * 40 + oct * 8) = v;
  }
  __syncthreads();

  const int g = l >> 4;
  const int cil = g * 8;
  const int col = l & 15;

  int abase[4];
#pragma unroll
  for (int jj = 0; jj < 4; ++jj) {
    int m = (w + jj * 4) * 16 + col;     // < 256 always
    int img = m >> 6, rel = m & 63;
    int wa = rel >> 2, e = rel & 3;
    int oy = wa >> 2, ox = wa & 3;
    int py = 2 * oy + (e >> 1) - 1; if (py < 0) py = 0;  // pad cell: clamp
    int px = 2 * ox + (e & 1) - 1;  if (px < 0) px = 0;  // (result discarded)
    abase[jj] = img * 4840 + (py * 11 + px) * 40 + cil;  // no +2: cancels
  }
  f32x4 acc[4][4];
#pragma unroll
  for (int q = 0; q < 4; ++q) {
    float bias = b3[q * 16 + col];
#pragma unroll
    for (int jj = 0; jj < 4; ++jj)
      acc[jj][q] = (f32x4){bias, bias, bias, bias};
  }
  const bf16x8* Bb = (const bf16x8*)Bp3;   // idx (c*4+nt)*64 + l
  bf16x8 bfr[4];
#pragma unroll
  for (int q = 0; q < 4; ++q) bfr[q] = Bb[q * 64 + l];
  for (int c = 0; c < 25; ++c) {
    bf16x8 nb0 = bfr[0], nb1 = bfr[1], nb2 = bfr[2], nb3 = bfr[3];
    if (c < 24) {
      nb0 = Bb[((c + 1) * 4 + 0) * 64 + l];
      nb1 = Bb[((c + 1) * 4 + 1) * 64 + l];
      nb2 = Bb[((c + 1) * 4 + 2) * 64 + l];
      nb3 = Bb[((c + 1) * 4 + 3) * 64 + l];
    }
    int ky = c / 5, kx = c - ky * 5;
    int off = (ky * 11 + kx) * 40;
#pragma unroll
    for (int jj = 0; jj < 4; ++jj) {
      bf16x8 a = *(const bf16x8*)(smem + abase[jj] + off);
      acc[jj][0] = MFMA16(a, bfr[0], acc[jj][0], 0, 0, 0);
      acc[jj][1] = MFMA16(a, bfr[1], acc[jj][1], 0, 0, 0);
      acc[jj][2] = MFMA16(a, bfr[2], acc[jj][2], 0, 0, 0);
      acc[jj][3] = MFMA16(a, bfr[3], acc[jj][3], 0, 0, 0);
    }
    bfr[0] = nb0; bfr[1] = nb1; bfr[2] = nb2; bfr[3] = nb3;
  }
  // pool+relu in registers; mask out pad elements (e valid per window coords)
#pragma unroll
  for (int jj = 0; jj < 4; ++jj) {
    int m0 = (w + jj * 4) * 16 + g * 4;
    int img = m0 >> 6, rel = m0 & 63;
    int wa = rel >> 2;
    int oy = wa >> 2, ox = wa & 3;
    size_t base = (((size_t)(bb * 4 + img)) << 10) + wa;
#pragma unroll
    for (int q = 0; q < 4; ++q) {
      float v = acc[jj][q][3];                       // e=3 (dy=1,dx=1) always valid
      if (ox > 0) v = fmaxf(v, acc[jj][q][2]);       // e=2 (1,0)
      if (oy > 0) v = fmaxf(v, acc[jj][q][1]);       // e=1 (0,1)
      if (oy > 0 && ox > 0) v = fmaxf(v, acc[jj][q][0]);  // e=0 (0,0)
      p3[base + (size_t)(q * 16 + col) * 16] = f2b(fmaxf(v, 0.f));
    }
  }
}

// ---------------- fc1 MFMA: M=8192,N=256,K=1024; no LDS, prefetch ---------
__global__ __launch_bounds__(256) void fc1_mfma(
    const u16* __restrict__ p3, const u16* __restrict__ Bp1,
    const float* __restrict__ fb1, float* __restrict__ h4) {
  const int bid = blockIdx.x;
  const int mb = bid >> 1, nb = bid & 1;   // 128 x 2
  const int t = threadIdx.x;
  const int w = t >> 6, l = t & 63;
  const int g = l >> 4;

  const int mt0 = mb * 4 + (w >> 1) * 2;     // 2 M-tiles
  const int ntbase = nb * 8 + (w & 1) * 4;   // 4 N-tiles

  size_t arow0 = (size_t)(mt0 * 16 + (l & 15)) * 1024 + g * 8;
  size_t arow1 = arow0 + 16 * 1024;
  const bf16x8* Bb = (const bf16x8*)Bp1;     // idx (c*16+nt)*64 + l

  f32x4 acc[2][4];
#pragma unroll
  for (int i = 0; i < 2; ++i)
#pragma unroll
    for (int q = 0; q < 4; ++q) acc[i][q] = (f32x4){0.f, 0.f, 0.f, 0.f};

  bf16x8 a0 = *(const bf16x8*)(p3 + arow0);
  bf16x8 a1 = *(const bf16x8*)(p3 + arow1);
  bf16x8 bq0 = Bb[(ntbase + 0) * 64 + l], bq1 = Bb[(ntbase + 1) * 64 + l];
  bf16x8 bq2 = Bb[(ntbase + 2) * 64 + l], bq3 = Bb[(ntbase + 3) * 64 + l];

  for (int c = 0; c < 32; ++c) {
    bf16x8 na0 = a0, na1 = a1, nb0 = bq0, nb1 = bq1, nb2 = bq2, nb3 = bq3;
    if (c < 31) {
      na0 = *(const bf16x8*)(p3 + arow0 + (c + 1) * 32);
      na1 = *(const bf16x8*)(p3 + arow1 + (c + 1) * 32);
      nb0 = Bb[((c + 1) * 16 + ntbase + 0) * 64 + l];
      nb1 = Bb[((c + 1) * 16 + ntbase + 1) * 64 + l];
      nb2 = Bb[((c + 1) * 16 + ntbase + 2) * 64 + l];
      nb3 = Bb[((c + 1) * 16 + ntbase + 3) * 64 + l];
    }
    acc[0][0] = MFMA16(a0, bq0, acc[0][0], 0, 0, 0);
    acc[0][1] = MFMA16(a0, bq1, acc[0][1], 0, 0, 0);
    acc[0][2] = MFMA16(a0, bq2, acc[0][2], 0, 0, 0);
    acc[0][3] = MFMA16(a0, bq3, acc[0][3], 0, 0, 0);
    acc[1][0] = MFMA16(a1, bq0, acc[1][0], 0, 0, 0);
    acc[1][1] = MFMA16(a1, bq1, acc[1][1], 0, 0, 0);
    acc[1][2] = MFMA16(a1, bq2, acc[1][2], 0, 0, 0);
    acc[1][3] = MFMA16(a1, bq3, acc[1][3], 0, 0, 0);
    a0 = na0; a1 = na1; bq0 = nb0; bq1 = nb1; bq2 = nb2; bq3 = nb3;
  }
#pragma unroll
  for (int i = 0; i < 2; ++i) {
    int mrow = (mt0 + i) * 16 + g * 4;
#pragma unroll
    for (int q = 0; q < 4; ++q) {
      int col = (ntbase + q) * 16 + (l & 15);
      float bias = fb1[col];
#pragma unroll
      for (int r = 0; r < 4; ++r)
        h4[(size_t)(mrow + r) * 256 + col] = fmaxf(acc[i][q][r] + bias, 0.f);
    }
  }
}

// ---------------- fc2 + log_softmax (fp32), one wave per row --------------
__global__ __launch_bounds__(256) void fc2_lsm(
    const float* __restrict__ h4, const float* __restrict__ fw2,
    const float* __restrict__ fb2, float* __restrict__ out) {
  const int wave = threadIdx.x >> 6;
  const int lane = threadIdx.x & 63;
  const int b = blockIdx.x * 4 + wave;
  const float* h = h4 + (size_t)b * 256;
  float acc[10];
#pragma unroll
  for (int o = 0; o < 10; ++o) acc[o] = 0.f;
#pragma unroll
  for (int j = 0; j < 4; ++j) {
    const float a = h[lane + j * 64];
#pragma unroll
    for (int o = 0; o < 10; ++o)
      acc[o] = fmaf(a, fw2[o * 256 + lane + j * 64], acc[o]);
  }
#pragma unroll
  for (int o = 0; o < 10; ++o)
    for (int s = 32; s > 0; s >>= 1) acc[o] += __shfl_down(acc[o], s, 64);
  if (lane == 0) {
    float v[10], m = -1e30f;
#pragma unroll
    for (int o = 0; o < 10; ++o) { v[o] = acc[o] + fb2[o]; m = fmaxf(m, v[o]); }
    float s = 0.f;
#pragma unroll
    for (int o = 0; o < 10; ++o) s += expf(v[o] - m);
    const float lse = m + logf(s);
#pragma unroll
    for (int o = 0; o < 10; ++o) out[(size_t)b * 10 + o] = v[o] - lse;
  }
}

extern "C" void kernel_launch(void* const* d_in, const int* in_sizes, int n_in,
                              void* d_out, int out_size, void* d_ws, size_t ws_size,
                              hipStream_t stream) {
  const float* x   = (const float*)d_in[0];
  const float* w1  = (const float*)d_in[1];
  const float* b1  = (const float*)d_in[2];
  const float* w2  = (const float*)d_in[3];
  const float* b2  = (const float*)d_in[4];
  const float* w3  = (const float*)d_in[5];
  const float* b3  = (const float*)d_in[6];
  const float* fw1 = (const float*)d_in[7];
  const float* fb1 = (const float*)d_in[8];
  const float* fw2 = (const float*)d_in[9];
  const float* fb2 = (const float*)d_in[10];
  float* out = (float*)d_out;

  // Workspace byte layout (~103 MB total):
  char* W = (char*)d_ws;
  u16*   p1  = (u16*)(W);                    // 8192*3136*2   = 51,380,224
  u16*   p2  = (u16*)(W + 51380224);         // 8192*1568*2   = 25,690,112
  u16*   p3  = (u16*)(W + 77070336);         // 8192*1024*2   = 16,777,216
  float* h4  = (float*)(W + 93847552);       // 8192*256*4    =  8,388,608
  u16*   Bp2 = (u16*)(W + 102236160);        // 26,624
  u16*   Bp3 = (u16*)(W + 102262784);        // 102,400
  u16*   Bp1 = (u16*)(W + 102365184);        // 524,288
  u16*   Bp0 = (u16*)(W + 102889472);        // 143,360

  mega_pack <<<dim3(1556), dim3(256), 0, stream>>>(w2, w3, fw1, w1, Bp2, Bp3, Bp1, Bp0);
  conv1_mfma<<<dim3(512),  dim3(448), 0, stream>>>(x, Bp0, b1, p1);
  conv2_mfma<<<dim3(4096), dim3(256), 0, stream>>>(p1, Bp2, b2, p2);
  conv3_mfma<<<dim3(2048), dim3(256), 0, stream>>>(p2, Bp3, b3, p3);
  fc1_mfma<<<dim3(256), dim3(256), 0, stream>>>(p3, Bp1, fb1, h4);
  fc2_lsm<<<dim3(2048), dim3(256), 0, stream>>>(h4, fw2, fb2, out);
}